// Round 7
// baseline (161.866 us; speedup 1.0000x reference)
//
#include <hip/hip_runtime.h>

// x:(8,32,32,64,64) f32 -> out:(8,32,48,96,96) f32
// variance=1: out = 2*log( trilinear( exp(x/2) ) ), identity grid, align_corners=True.
//
// Zero-barrier wave-private design. Block = one (nc,zo); wave w owns output rows
// [w*24, w*24+24), processed as 3 chunks of 8 rows:
//   LOAD  (chunk): 32 coalesced global dword loads (4 zy-corners x 8 rows, x = lane)
//   STAGE (chunk): 4 exps + zy-bilinear per value -> wave-private F2[w][8][68] in LDS
//   CONSUME(chunk): 8 rows x 24 quads = 192 quads = 3/lane; per output 1 ds_read2
//                   + x-lerp + 2*log; contiguous dwordx4 stores.
// Pipeline: L0 S0 L1 C0 S1 L2 C1 S2 C2  (loads of k+1 in flight under consume of k).
// No __syncthreads anywhere: same-wave DS ops are in-order, so the single-buffer
// WAR (C(k) reads before S(k+1) overwrites) is safe.
constexpr int N = 8, C = 32, Din = 32, Hin = 64, Win = 64;
constexpr int Do = 48, Ho = 96, Wo = 96;
constexpr int BLOCK = 256, NBLOCKS = N * C * Do;   // 12288 blocks: one per (nc,zo)
constexpr int RPC = 8;                             // rows per chunk (per wave)
constexpr int PAD = 68;                            // bank-spread 4/row, rows 16B-aligned

typedef float f32x4 __attribute__((ext_vector_type(4)));

__global__ __launch_bounds__(BLOCK, 5)
void resample3d_var_kernel(const float* __restrict__ in, float* __restrict__ out) {
    __shared__ float F2[4][RPC][PAD];              // 8704 B, wave-private slices

    const int tid  = threadIdx.x;
    const int w    = tid >> 6;
    const int lane = tid & 63;
    const int bid  = blockIdx.x;
    const int zo   = bid % Do;
    const int nc   = bid / Do;

    // z weights (block-uniform; exact at zo=47 -> fz==31.0)
    float fz  = (float)(zo * (Din - 1)) * (1.0f / (float)(Do - 1));
    int   z0  = (int)fz;
    float wz1 = fz - (float)z0;
    int   z1  = min(z0 + 1, Din - 1);

    const float* __restrict__ p0 = in + ((size_t)nc * Din + z0) * (Hin * Win);
    const float* __restrict__ p1 = in + ((size_t)nc * Din + z1) * (Hin * Win);

    const int r0w = w * 24;                        // first output row this wave owns
    float* __restrict__ ob = out + ((size_t)nc * Do + zo) * (size_t)(Ho * Wo);

    constexpr float HALF_LOG2E = 0.7213475204444817f;  // exp(x/2) = exp2(x*K)
    constexpr float TWO_LN2    = 1.3862943611198906f;  // 2*logf(v) = TWO_LN2*log2f(v)

    float a0[RPC], a1[RPC], b0[RPC], b1[RPC];      // load set A
    float c0[RPC], c1[RPC], d0[RPC], d1[RPC];      // load set B

#define LOADCH(ch, A0, A1, B0, B1)                                     \
    _Pragma("unroll")                                                  \
    for (int j = 0; j < RPC; ++j) {                                    \
        int   yo = r0w + (ch) * RPC + j;                               \
        float fy = (float)(yo * (Hin - 1)) * (1.0f / (float)(Ho - 1)); \
        int   y0 = (int)fy;                                            \
        int   y1 = min(y0 + 1, Hin - 1);                               \
        A0[j] = p0[y0 * Win + lane];                                   \
        A1[j] = p0[y1 * Win + lane];                                   \
        B0[j] = p1[y0 * Win + lane];                                   \
        B1[j] = p1[y1 * Win + lane];                                   \
    }

#define STAGECH(ch, A0, A1, B0, B1)                                    \
    _Pragma("unroll")                                                  \
    for (int j = 0; j < RPC; ++j) {                                    \
        int   yo  = r0w + (ch) * RPC + j;                              \
        float fy  = (float)(yo * (Hin - 1)) * (1.0f / (float)(Ho - 1));\
        float wy1 = fy - (float)(int)fy;                               \
        float e00 = __builtin_amdgcn_exp2f(A0[j] * HALF_LOG2E);        \
        float e01 = __builtin_amdgcn_exp2f(A1[j] * HALF_LOG2E);        \
        float e10 = __builtin_amdgcn_exp2f(B0[j] * HALF_LOG2E);        \
        float e11 = __builtin_amdgcn_exp2f(B1[j] * HALF_LOG2E);        \
        float f0  = e00 + wy1 * (e01 - e00);                           \
        float f1  = e10 + wy1 * (e11 - e10);                           \
        F2[w][j][lane] = f0 + wz1 * (f1 - f0);                         \
    }

#define CONSUMECH(ch)                                                  \
    _Pragma("unroll")                                                  \
    for (int i = 0; i < 3; ++i) {                                      \
        int t   = i * 64 + lane;                                       \
        int row = (t * 2731) >> 16;        /* t/24, exact for t<2304 */\
        int q   = t - row * 24;                                        \
        f32x4 o;                                                       \
        _Pragma("unroll")                                              \
        for (int ii = 0; ii < 4; ++ii) {                               \
            int   xo  = q * 4 + ii;                                    \
            float fx  = (float)(xo * (Win - 1)) * (1.0f / (float)(Wo - 1)); \
            int   x0  = (int)fx;                                       \
            float wx1 = fx - (float)x0;                                \
            int   x1  = min(x0 + 1, Win - 1);                          \
            float F0 = F2[w][row][x0], F1 = F2[w][row][x1];            \
            o[ii] = TWO_LN2 * __log2f(F0 + wx1 * (F1 - F0));           \
        }                                                              \
        *reinterpret_cast<f32x4*>(ob + ((r0w + (ch) * RPC) * Wo) + t * 4) = o; \
    }

    LOADCH(0, a0, a1, b0, b1)
    STAGECH(0, a0, a1, b0, b1)
    LOADCH(1, c0, c1, d0, d1)
    CONSUMECH(0)
    STAGECH(1, c0, c1, d0, d1)
    LOADCH(2, a0, a1, b0, b1)
    CONSUMECH(1)
    STAGECH(2, a0, a1, b0, b1)
    CONSUMECH(2)

#undef LOADCH
#undef STAGECH
#undef CONSUMECH
}

extern "C" void kernel_launch(void* const* d_in, const int* in_sizes, int n_in,
                              void* d_out, int out_size, void* d_ws, size_t ws_size,
                              hipStream_t stream) {
    const float* x = (const float*)d_in[0];
    float* out = (float*)d_out;
    resample3d_var_kernel<<<NBLOCKS, BLOCK, 0, stream>>>(x, out);
}

// Round 8
// 139.653 us; speedup vs baseline: 1.1591x; 1.1591x over previous
//
#include <hip/hip_runtime.h>

// x:(8,32,32,64,64) f32 -> out:(8,32,48,96,96) f32
// variance=1: out = 2*log( trilinear( exp(x/2) ) ), identity grid, align_corners=True.
//
// Block = one (nc, zo, yhalf). 24576 blocks, 21.5 KB LDS -> 7 blocks/CU (28 waves).
//  Phase 1: G[yl][x] = wz0*exp(in[z0,ybase+yl,x]/2) + wz1*exp(in[z1,ybase+yl,x]/2)
//           (33 staged rows; float4 loads)                                  [barrier]
//  Phase 2: F2[yr][x] = y-lerp of G for this half's 48 output rows          [barrier]
//  Phase 3: 1152 float4 quads: ds_read2 x0/x1 + x-lerp + 2*log, contiguous dwordx4 stores.
// XCD-chunked swizzle groups blocks sharing input z-planes on one XCD's L2.
constexpr int N = 8, C = 32, Din = 32, Hin = 64, Win = 64;
constexpr int Do = 48, Ho = 96, Wo = 96;

constexpr int BLOCK   = 256;
constexpr int NBLOCKS = N * C * Do * 2;        // 24576 (divisible by 8)
constexpr int GROWS   = 33;                    // staged input rows per half
constexpr int GCHUNKS = GROWS * (Win / 4);     // 528 float4 chunks
constexpr int HROWS   = 48;                    // output rows per half
constexpr int F2PAD   = 68;
constexpr int QUADS   = HROWS * (Wo / 4);      // 1152

typedef float f32x4 __attribute__((ext_vector_type(4)));

__global__ __launch_bounds__(BLOCK, 7)
void resample3d_var_kernel(const float* __restrict__ in, float* __restrict__ out) {
    __shared__ float G[GROWS][Win];            // 8448 B
    __shared__ float F2[HROWS][F2PAD];         // 13056 B

    const int tid = threadIdx.x;

    // XCD-chunked bijective swizzle: XCD k owns a contiguous sid range.
    const int bid = blockIdx.x;
    const int sid = (bid & 7) * (NBLOCKS / 8) + (bid >> 3);

    const int yhalf = sid & 1;
    const int pz    = sid >> 1;                // (nc*Do + zo)
    const int zo    = pz % Do;
    const int nc    = pz / Do;
    const int ybase = yhalf ? 31 : 0;          // half 0: rows 0..32; half 1: rows 31..63

    // z weights (block-uniform; exact at zo=47 -> fz==31.0)
    float fz  = (float)(zo * (Din - 1)) * (1.0f / (float)(Do - 1));
    int   z0  = (int)fz;
    float wz1 = fz - (float)z0;
    int   z1  = min(z0 + 1, Din - 1);
    float wz0 = 1.0f - wz1;

    const float* __restrict__ p0 = in + ((size_t)nc * Din + z0) * (Hin * Win) + ybase * Win;
    const float* __restrict__ p1 = in + ((size_t)nc * Din + z1) * (Hin * Win) + ybase * Win;

    constexpr float HALF_LOG2E = 0.7213475204444817f;   // exp(x/2)  = exp2(x*K)
    constexpr float TWO_LN2    = 1.3862943611198906f;   // 2*logf(v) = TWO_LN2*log2f(v)

    // ---- Phase 1: stage 33 z-combined exp rows (528 float4 chunks) ----
#pragma unroll
    for (int k = 0; k < 3; ++k) {
        int c = k * BLOCK + tid;
        if (c < GCHUNKS) {
            int y  = c >> 4;                   // 0..32
            int sx = (c & 15) << 2;            // 0,4,...,60
            const float4 a = *reinterpret_cast<const float4*>(p0 + y * Win + sx);
            const float4 b = *reinterpret_cast<const float4*>(p1 + y * Win + sx);
            float4 g;
            g.x = wz0 * __builtin_amdgcn_exp2f(a.x * HALF_LOG2E) + wz1 * __builtin_amdgcn_exp2f(b.x * HALF_LOG2E);
            g.y = wz0 * __builtin_amdgcn_exp2f(a.y * HALF_LOG2E) + wz1 * __builtin_amdgcn_exp2f(b.y * HALF_LOG2E);
            g.z = wz0 * __builtin_amdgcn_exp2f(a.z * HALF_LOG2E) + wz1 * __builtin_amdgcn_exp2f(b.z * HALF_LOG2E);
            g.w = wz0 * __builtin_amdgcn_exp2f(a.w * HALF_LOG2E) + wz1 * __builtin_amdgcn_exp2f(b.w * HALF_LOG2E);
            *reinterpret_cast<float4*>(&G[y][sx]) = g;
        }
    }
    __syncthreads();

    // ---- Phase 2: F2 for this half's 48 output rows (12 values/thread) ----
    {
        const int x = tid & 63;
        const int w = tid >> 6;
#pragma unroll
        for (int j = 0; j < 12; ++j) {
            int   yrow = j * 4 + w;                     // wave-uniform row
            int   yo   = yhalf * HROWS + yrow;
            float fy   = (float)(yo * (Hin - 1)) * (1.0f / (float)(Ho - 1));
            int   y0   = (int)fy;
            float wy1  = fy - (float)y0;
            int   y1   = min(y0 + 1, Hin - 1);
            float g0 = G[y0 - ybase][x], g1 = G[y1 - ybase][x];
            F2[yrow][x] = g0 + wy1 * (g1 - g0);
        }
    }
    __syncthreads();

    // ---- Phase 3: 1152 quads, contiguous dwordx4 stores ----
    float* __restrict__ ob = out + (((size_t)nc * Do + zo) * Ho + yhalf * HROWS) * Wo;
#pragma unroll
    for (int k = 0; k < 5; ++k) {
        int c = k * BLOCK + tid;
        if (c < QUADS) {
            int row = (c * 2731) >> 16;        // c/24, exact for c < 2304
            int q   = c - row * 24;
            f32x4 o;
#pragma unroll
            for (int i = 0; i < 4; ++i) {
                int   xo  = q * 4 + i;
                float fx  = (float)(xo * (Win - 1)) * (1.0f / (float)(Wo - 1));
                int   x0  = (int)fx;
                float wx1 = fx - (float)x0;
                int   x1  = min(x0 + 1, Win - 1);
                float F0 = F2[row][x0], F1 = F2[row][x1];   // adjacent -> ds_read2_b32
                o[i] = TWO_LN2 * __log2f(F0 + wx1 * (F1 - F0));
            }
            *reinterpret_cast<f32x4*>(ob + (size_t)c * 4) = o;
        }
    }
}

extern "C" void kernel_launch(void* const* d_in, const int* in_sizes, int n_in,
                              void* d_out, int out_size, void* d_ws, size_t ws_size,
                              hipStream_t stream) {
    const float* x = (const float*)d_in[0];
    float* out = (float*)d_out;
    resample3d_var_kernel<<<NBLOCKS, BLOCK, 0, stream>>>(x, out);
}

// Round 9
// 123.728 us; speedup vs baseline: 1.3082x; 1.1287x over previous
//
#include <hip/hip_runtime.h>

// x:(8,32,32,64,64) f32 -> out:(8,32,48,96,96) f32
// variance=1: out = 2*log( trilinear( exp(x/2) ) ), identity grid, align_corners=True.
//
// Block = one (nc, zo). R4 3-phase structure, issue-trimmed:
//  Phase 1: G[y][x] = wz0*exp(in[z0,y,x]/2) + wz1*exp(in[z1,y,x]/2)   (G[64][68], 17.4 KB)
//  Phase 2 (per y-half): F2[r][xc..xc+3] via 2x ds_read_b128 + ds_write_b128 (F2[48][68], 13 KB)
//           + edge dup F2[r][64]=F2[r][63] so phase 3 never needs min() on x1.
//  Phase 3 (per y-half): 1152 quads; x-interp params hoisted into 3 q-phase register sets
//           (q=(16k+tid)%24 has period 3 in k); per output ds_read2 + lerp + 2*log;
//           contiguous dwordx4 stores.
// LDS 30464 B -> 5 blocks/CU.
constexpr int N = 8, C = 32, Din = 32, Hin = 64, Win = 64;
constexpr int Do = 48, Ho = 96, Wo = 96;

constexpr int BLOCK   = 256;
constexpr int NBLOCKS = N * C * Do;          // 12288: one per (nc, zo)
constexpr int GPAD    = 68;                  // rows 16B-aligned, banks shift 4/row
constexpr int F2PAD   = 68;
constexpr int HROWS   = 48;                  // output rows per half
constexpr int QUADS   = HROWS * (Wo / 4);    // 1152 per half

typedef float f32x4 __attribute__((ext_vector_type(4)));

__global__ __launch_bounds__(BLOCK, 5)
void resample3d_var_kernel(const float* __restrict__ in, float* __restrict__ out) {
    __shared__ float G[Hin][GPAD];           // 17408 B
    __shared__ float F2[HROWS][F2PAD];       // 13056 B

    const int tid = threadIdx.x;
    const int bid = blockIdx.x;
    const int zo  = bid % Do;
    const int nc  = bid / Do;

    // z weights (block-uniform)
    float fz  = (float)(zo * (Din - 1)) * (1.0f / (float)(Do - 1));
    int   z0  = (int)fz;
    float wz1 = fz - (float)z0;
    int   z1  = min(z0 + 1, Din - 1);
    float wz0 = 1.0f - wz1;

    const float* __restrict__ p0 = in + ((size_t)nc * Din + z0) * (Hin * Win);
    const float* __restrict__ p1 = in + ((size_t)nc * Din + z1) * (Hin * Win);

    constexpr float HALF_LOG2E = 0.7213475204444817f;   // exp(x/2)  = exp2(x*K)
    constexpr float TWO_LN2    = 1.3862943611198906f;   // 2*logf(v) = TWO_LN2*log2f(v)

    // ---- Phase 1: stage G (4096 floats = 1024 float4 chunks, exactly 4/thread) ----
    {
        const int sy = tid >> 4;             // 0..15
        const int sx = (tid & 15) << 2;      // 0,4,...,60
#pragma unroll
        for (int k = 0; k < 4; ++k) {
            int y = sy + k * 16;
            const float4 a = *reinterpret_cast<const float4*>(p0 + y * Win + sx);
            const float4 b = *reinterpret_cast<const float4*>(p1 + y * Win + sx);
            float4 g;
            g.x = wz0 * __builtin_amdgcn_exp2f(a.x * HALF_LOG2E) + wz1 * __builtin_amdgcn_exp2f(b.x * HALF_LOG2E);
            g.y = wz0 * __builtin_amdgcn_exp2f(a.y * HALF_LOG2E) + wz1 * __builtin_amdgcn_exp2f(b.y * HALF_LOG2E);
            g.z = wz0 * __builtin_amdgcn_exp2f(a.z * HALF_LOG2E) + wz1 * __builtin_amdgcn_exp2f(b.z * HALF_LOG2E);
            g.w = wz0 * __builtin_amdgcn_exp2f(a.w * HALF_LOG2E) + wz1 * __builtin_amdgcn_exp2f(b.w * HALF_LOG2E);
            *reinterpret_cast<float4*>(&G[y][sx]) = g;
        }
    }
    __syncthreads();

    // ---- Hoisted x-interp params: 3 q-phases (q = (16k+tid)%24, period 3 in k) ----
    int   x0r[3][4];
    float wxr[3][4];
    {
        int q0 = tid % 24;
        int q1 = q0 + 16; if (q1 >= 24) q1 -= 24;
        int q2 = q0 + 8;  if (q2 >= 24) q2 -= 24;
        int qs[3] = {q0, q1, q2};
#pragma unroll
        for (int p = 0; p < 3; ++p) {
#pragma unroll
            for (int i = 0; i < 4; ++i) {
                int   xo = qs[p] * 4 + i;
                float fx = (float)(xo * (Win - 1)) * (1.0f / (float)(Wo - 1));
                int   x0 = (int)fx;
                x0r[p][i] = x0;
                wxr[p][i] = fx - (float)x0;
            }
        }
    }

    const size_t obase = ((size_t)nc * Do + zo) * (size_t)(Ho * Wo);

#pragma unroll
    for (int h = 0; h < 2; ++h) {
        // ---- Phase 2: F2 for this half (48 rows x 64), float4 granularity ----
        {
            const int xc = (tid & 15) << 2;  // 0,4,...,60
            const int r0 = tid >> 4;         // 0..15
#pragma unroll
            for (int j = 0; j < 3; ++j) {
                int   r   = r0 + 16 * j;                 // 0..47
                int   yo  = h * HROWS + r;
                float fy  = (float)(yo * (Hin - 1)) * (1.0f / (float)(Ho - 1));
                int   y0  = (int)fy;
                float wy1 = fy - (float)y0;
                int   y1  = min(y0 + 1, Hin - 1);
                f32x4 g0 = *reinterpret_cast<const f32x4*>(&G[y0][xc]);
                f32x4 g1 = *reinterpret_cast<const f32x4*>(&G[y1][xc]);
                f32x4 f  = g0 + wy1 * (g1 - g0);
                *reinterpret_cast<f32x4*>(&F2[r][xc]) = f;
                if (xc == 60) F2[r][64] = f.w;           // edge dup: x1=x0+1 always valid
            }
        }
        __syncthreads();

        // ---- Phase 3: 1152 quads, hoisted x-params, contiguous dwordx4 stores ----
        float* __restrict__ ob = out + obase + (size_t)h * (HROWS * Wo);
#pragma unroll
        for (int k = 0; k < 5; ++k) {
            int c = k * BLOCK + tid;
            if (c < QUADS) {                             // k==4: tid<128 tail
                int row = (c * 2731) >> 16;              // c/24, exact for c < 2304
                const float* __restrict__ rp = &F2[row][0];
                f32x4 o;
#pragma unroll
                for (int i = 0; i < 4; ++i) {
                    int   x0  = x0r[k % 3][i];
                    float wx1 = wxr[k % 3][i];
                    float F0 = rp[x0], F1 = rp[x0 + 1];  // adjacent -> ds_read2_b32
                    o[i] = TWO_LN2 * __log2f(F0 + wx1 * (F1 - F0));
                }
                *reinterpret_cast<f32x4*>(ob + (size_t)c * 4) = o;
            }
        }
        if (h == 0) __syncthreads();                     // WAR on F2
    }
}

extern "C" void kernel_launch(void* const* d_in, const int* in_sizes, int n_in,
                              void* d_out, int out_size, void* d_ws, size_t ws_size,
                              hipStream_t stream) {
    const float* x = (const float*)d_in[0];
    float* out = (float*)d_out;
    resample3d_var_kernel<<<NBLOCKS, BLOCK, 0, stream>>>(x, out);
}